// Round 1
// baseline (1511.053 us; speedup 1.0000x reference)
//
#include <hip/hip_runtime.h>
#include <cmath>

#define K_MIX 16
#define P_DIM 256
#define Q_DIM 8
#define NB 8              // samples per block -> 64 columns
#define TRI 32896         // P(P+1)/2

typedef short bf16x8 __attribute__((ext_vector_type(8)));
typedef float f32x4 __attribute__((ext_vector_type(4)));

__device__ __forceinline__ ushort f2bf(float f) {
    unsigned u = __float_as_uint(f);
    u = (u + 0x7fffu + ((u >> 16) & 1u)) >> 16;
    return (ushort)u;
}

// ---------------- prep: S_vec -> dense bf16 S^T[k][p][r] ----------------
__global__ void prep_st(const float* __restrict__ Sv, ushort* __restrict__ St) {
    int t = blockIdx.x * 256 + threadIdx.x;      // < 16*256*256
    int k = t >> 16, idx = t & 65535, p = idx >> 8, r = idx & 255;
    float v = 0.f;
    if (r >= p) v = Sv[k * TRI + (r * (r + 1)) / 2 + p];
    St[t] = f2bf(v);
}

// ---------------- prep: coef[k] = LOGSA - 4*log_det_S[k] + log_softmax(pi)[k] ----------------
__global__ void prep_coef(const float* __restrict__ Sv, const float* __restrict__ pi,
                          float* __restrict__ coef, float logsa) {
    int t = threadIdx.x;
    if (t < 16) {
        float mx = pi[0];
        for (int k = 1; k < 16; ++k) mx = fmaxf(mx, pi[k]);
        float sm = 0.f;
        for (int k = 0; k < 16; ++k) sm += __expf(pi[k] - mx);
        float lsep = mx + logf(sm);
        float acc = 0.f;
        for (int r = 0; r < 256; ++r)
            acc += logf(fabsf(Sv[t * TRI + (r * (r + 3)) / 2]));   // diag idx = r(r+1)/2 + r
        // log_det_S = -2*acc ; coef = LOGSA - 4*log_det_S + (pi - lse) = LOGSA + 8*acc + pi - lse
        coef[t] = logsa + 8.f * acc + (pi[t] - lsep);
    }
}

// ---------------- main fused kernel ----------------
__global__ __launch_bounds__(256, 2) void macg_main(
    const float* __restrict__ X, const ushort* __restrict__ St,
    const float* __restrict__ coef, float* __restrict__ out)
{
    __shared__ __align__(16) ushort Xs[16384];   // 32KB: X^T bf16 staging; later Ytri f32[128*36] + dens f32[128]
    __shared__ __align__(16) float  ZY[4096];    // 16KB: per-wave Z-stage (bf16) aliased with Y-partials (f32)

    const int tid  = threadIdx.x;
    const int lane = tid & 63;
    const int w    = tid >> 6;       // wave 0..3
    const int cg   = lane & 15;
    const int g4   = lane >> 4;

    // ---- stage X block into Xs as X^T bf16, XOR-swizzled: idx = col*256 + (r ^ ((col&7)<<3)) ----
    const float* Xb = X + (size_t)blockIdx.x * (NB * P_DIM * Q_DIM);
    #pragma unroll
    for (int it = 0; it < 16; ++it) {
        int g  = it * 256 + tid;              // 4096 float4 chunks of the 64KB block
        int q4 = (g & 1) * 4;
        int r  = (g >> 1) & 255;
        int n  = g >> 9;
        float4 v = *(const float4*)(Xb + n * 2048 + r * 8 + q4);
        #pragma unroll
        for (int c = 0; c < 4; ++c) {
            int col = n * 8 + q4 + c;
            float f = (c == 0) ? v.x : (c == 1) ? v.y : (c == 2) ? v.z : v.w;
            Xs[col * 256 + (r ^ ((col & 7) << 3))] = f2bf(f);
        }
    }
    __syncthreads();

    // ---- preload ALL X (B-operand) fragments into registers: identical for every k ----
    bf16x8 B[8][4];
    #pragma unroll
    for (int ks = 0; ks < 8; ++ks) {
        #pragma unroll
        for (int nt = 0; nt < 4; ++nt) {
            int col = nt * 16 + cg;
            int idx = col * 256 + ((32 * ks + 8 * g4) ^ ((col & 7) << 3));
            B[ks][nt] = *(const bf16x8*)&Xs[idx];
        }
    }
    __syncthreads();   // all waves done reading Xs; region reused below

    float* Yt   = (float*)Xs;        // [128][36] lower-tri Y per (k,s)
    float* dens = Yt + 128 * 36;     // [8][16]

    // balanced triangular M-tile assignment: wave w owns {w, 7-w, 8+w, 15-w} (18 tile-ksteps each)
    const int m0 = w, m1 = 7 - w, m2 = 8 + w, m3 = 15 - w;
    const int km0 = m0 >> 1, km1 = m1 >> 1, km2 = m2 >> 1, km3 = m3 >> 1;

    for (int k = 0; k < K_MIX; ++k) {
        const ushort* Sk = St + (size_t)k * 65536;
        const f32x4 vz = {0.f, 0.f, 0.f, 0.f};
        f32x4 acc[4][4];
        #pragma unroll
        for (int i = 0; i < 4; ++i)
            #pragma unroll
            for (int j = 0; j < 4; ++j) acc[i][j] = vz;

        // ---- Z-GEMM: Z = S_k^T * Xb, triangular tiles skipped ----
        #pragma unroll
        for (int ks = 0; ks < 8; ++ks) {
            bf16x8 A0, A1, A2, A3;
            if (ks >= km0) A0 = *(const bf16x8*)(Sk + (16 * m0 + cg) * 256 + 32 * ks + 8 * g4);
            if (ks >= km1) A1 = *(const bf16x8*)(Sk + (16 * m1 + cg) * 256 + 32 * ks + 8 * g4);
            if (ks >= km2) A2 = *(const bf16x8*)(Sk + (16 * m2 + cg) * 256 + 32 * ks + 8 * g4);
            if (ks >= km3) A3 = *(const bf16x8*)(Sk + (16 * m3 + cg) * 256 + 32 * ks + 8 * g4);
            #pragma unroll
            for (int nt = 0; nt < 4; ++nt) {
                if (ks >= km0) acc[0][nt] = __builtin_amdgcn_mfma_f32_16x16x32_bf16(A0, B[ks][nt], acc[0][nt], 0, 0, 0);
                if (ks >= km1) acc[1][nt] = __builtin_amdgcn_mfma_f32_16x16x32_bf16(A1, B[ks][nt], acc[1][nt], 0, 0, 0);
                if (ks >= km2) acc[2][nt] = __builtin_amdgcn_mfma_f32_16x16x32_bf16(A2, B[ks][nt], acc[2][nt], 0, 0, 0);
                if (ks >= km3) acc[3][nt] = __builtin_amdgcn_mfma_f32_16x16x32_bf16(A3, B[ks][nt], acc[3][nt], 0, 0, 0);
            }
        }

        // ---- Y = Z^T Z : stage 32 rows at a time (wave-private LDS), MFMA with frag as both A and B ----
        ushort* Zs = (ushort*)ZY + w * 2048;   // 4KB wave-private: [nt][c16][r32]
        f32x4 yacc[4];
        #pragma unroll
        for (int nt = 0; nt < 4; ++nt) yacc[nt] = vz;

        #pragma unroll
        for (int h = 0; h < 2; ++h) {
            #pragma unroll
            for (int ii = 0; ii < 2; ++ii) {
                #pragma unroll
                for (int nt = 0; nt < 4; ++nt) {
                    f32x4 a = acc[2 * h + ii][nt];
                    ushort4 z;
                    z.x = f2bf(a[0]); z.y = f2bf(a[1]); z.z = f2bf(a[2]); z.w = f2bf(a[3]);
                    *(ushort4*)&Zs[nt * 512 + cg * 32 + ii * 16 + 4 * g4] = z;
                }
            }
            #pragma unroll
            for (int nt = 0; nt < 4; ++nt) {
                bf16x8 F = *(const bf16x8*)&Zs[nt * 512 + cg * 32 + 8 * g4];
                yacc[nt] = __builtin_amdgcn_mfma_f32_16x16x32_bf16(F, F, yacc[nt], 0, 0, 0);
            }
        }

        // ---- cross-wave Y reduction ----
        float* Yp = ZY + w * 1024;             // overwrite own Z-stage region with f32 partials
        #pragma unroll
        for (int nt = 0; nt < 4; ++nt)
            *(f32x4*)&Yp[nt * 256 + lane * 4] = yacc[nt];
        __syncthreads();
        {
            int nt = tid >> 6;
            int ln = tid & 63;
            f32x4 s = vz;
            #pragma unroll
            for (int wv = 0; wv < 4; ++wv)
                s += *(const f32x4*)&ZY[wv * 1024 + nt * 256 + ln * 4];
            int i4 = (ln >> 4) * 4, j = ln & 15;
            #pragma unroll
            for (int rg = 0; rg < 4; ++rg) {
                int i = i4 + rg;
                if ((i >> 3) == (j >> 3)) {
                    int ii = i & 7, jj = j & 7;
                    if (ii >= jj) {
                        int sl = 2 * nt + (i >> 3);
                        Yt[(k * 8 + sl) * 36 + (ii * (ii + 1)) / 2 + jj] = s[rg];
                    }
                }
            }
        }
        __syncthreads();
    }

    // ---- per-(k,s) Cholesky logdet (fully unrolled, static indices) ----
    if (tid < 128) {
        int k = tid >> 3, s = tid & 7;
        float a[36];
        #pragma unroll
        for (int j = 0; j < 36; ++j) a[j] = Yt[tid * 36 + j];
        float ls = 0.f;
        #pragma unroll
        for (int j = 0; j < 8; ++j) {
            const int tj = (j * (j + 1)) / 2;
            float d = a[tj + j];
            #pragma unroll
            for (int mm = 0; mm < j; ++mm) d -= a[tj + mm] * a[tj + mm];
            d = fmaxf(d, 1e-30f);
            float Ljj = sqrtf(d);
            ls += logf(Ljj);
            float inv = 1.f / Ljj;
            a[tj + j] = Ljj;
            #pragma unroll
            for (int i = j + 1; i < 8; ++i) {
                const int ti = (i * (i + 1)) / 2;
                float v = a[ti + j];
                #pragma unroll
                for (int mm = 0; mm < j; ++mm) v -= a[ti + mm] * a[tj + mm];
                a[ti + j] = v * inv;
            }
        }
        // density = coef[k] - C * logdet = coef[k] - 128 * (2*ls)
        dens[s * 16 + k] = coef[k] - 256.0f * ls;
    }
    __syncthreads();

    // ---- per-sample logsumexp over k, block sum, one atomic ----
    float v = 0.f;
    if (tid < 64) {
        if (tid < 8) {
            float mx = -1e30f;
            #pragma unroll
            for (int k = 0; k < 16; ++k) mx = fmaxf(mx, dens[tid * 16 + k]);
            float sm = 0.f;
            #pragma unroll
            for (int k = 0; k < 16; ++k) sm += __expf(dens[tid * 16 + k] - mx);
            v = mx + logf(sm);
        }
        v += __shfl_down(v, 4);
        v += __shfl_down(v, 2);
        v += __shfl_down(v, 1);
        if (tid == 0) atomicAdd(out, v);
    }
}

extern "C" void kernel_launch(void* const* d_in, const int* in_sizes, int n_in,
                              void* d_out, int out_size, void* d_ws, size_t ws_size,
                              hipStream_t stream)
{
    const float* X  = (const float*)d_in[0];
    const float* Sv = (const float*)d_in[1];
    const float* pi = (const float*)d_in[2];
    float* out = (float*)d_out;

    ushort* St  = (ushort*)d_ws;                                  // 2 MB bf16 S^T
    float*  cf  = (float*)((char*)d_ws + (size_t)16 * 65536 * 2); // 64 B

    int N = in_sizes[0] / (P_DIM * Q_DIM);   // 50000, divisible by NB=8

    // LOGSA in double on host
    double lg = (8.0 * 7.0 / 4.0) * log(M_PI);
    for (int i = 0; i < 8; ++i) lg += lgamma(128.0 - 0.5 * i);
    double logsa = lg - 8.0 * log(2.0) - (8.0 * 256.0 / 2.0) * log(M_PI);

    hipMemsetAsync(d_out, 0, sizeof(float), stream);
    prep_st<<<4096, 256, 0, stream>>>(Sv, St);
    prep_coef<<<1, 64, 0, stream>>>(Sv, pi, cf, (float)logsa);
    macg_main<<<N / NB, 256, 0, stream>>>(X, St, cf, out);
}